// Round 2
// baseline (252.766 us; speedup 1.0000x reference)
//
#include <hip/hip_runtime.h>
#include <math.h>

#define D 64
#define K 512
#define KT 128            // K-tile resident in LDS (64 x 128 fp32 = 32 KB)
#define NTILES (K / KT)   // 4
#define ROWS 131072       // 32*64*64
#define NELEM (ROWS * D)  // 8388608

// ws layout: [0,8) double loss accumulator ; [16, 16+K*4) float cnormB[K]

// B_j = np.sum(codebook**2, axis=0): elementwise square, then sequential
// accumulation over k ascending (numpy outer-axis reduce order). fp32, no fma.
__global__ __launch_bounds__(512) void vq_cnorm(const float* __restrict__ cb,
                                                float* __restrict__ cnorm) {
#pragma clang fp contract(off)
    int j = threadIdx.x;            // one block of 512
    float c0 = cb[j];
    float b = c0 * c0;
    for (int k = 1; k < D; ++k) {
        float ck = cb[k * K + j];
        b = b + ck * ck;            // sequential adds, contract off
    }
    cnorm[j] = b;
}

__global__ __launch_bounds__(256) void vq_main(const float* __restrict__ x,
                                               const float* __restrict__ cb,
                                               const float* __restrict__ cnorm,
                                               float* __restrict__ out,
                                               double* __restrict__ loss_acc) {
#pragma clang fp contract(off)
    __shared__ float ldsC[D * KT];       // 32 KB tile, [d][jl], broadcast reads
    __shared__ float wavesum[4];

    const int tid = threadIdx.x;
    const size_t row0 = (size_t)blockIdx.x * 512 + tid;   // 2 rows per thread
    const size_t row1 = row0 + 256;

    // ---- load both rows into registers ----
    float xr0[D], xr1[D];
    {
        const float4* xv0 = (const float4*)(x + row0 * D);
        const float4* xv1 = (const float4*)(x + row1 * D);
        #pragma unroll
        for (int i = 0; i < D / 4; ++i) {
            float4 v = xv0[i];
            xr0[4*i+0] = v.x; xr0[4*i+1] = v.y; xr0[4*i+2] = v.z; xr0[4*i+3] = v.w;
            float4 w = xv1[i];
            xr1[4*i+0] = w.x; xr1[4*i+1] = w.y; xr1[4*i+2] = w.z; xr1[4*i+3] = w.w;
        }
    }

    // ---- A = np.sum(x**2, axis=1), numpy pairwise_sum n=64 emulation ----
    // r[l] = sq[l] + sq[l+8] + ... + sq[l+56] (sequential), then
    // ((r0+r1)+(r2+r3)) + ((r4+r5)+(r6+r7)).  Squares are separate fp32 muls.
    float A0, A1;
    {
        float r[8], s[8];
        #pragma unroll
        for (int l = 0; l < 8; ++l) { r[l] = xr0[l] * xr0[l]; s[l] = xr1[l] * xr1[l]; }
        #pragma unroll
        for (int m = 1; m < 8; ++m) {
            #pragma unroll
            for (int l = 0; l < 8; ++l) {
                float q0 = xr0[8*m + l] * xr0[8*m + l];
                float q1 = xr1[8*m + l] * xr1[8*m + l];
                r[l] = r[l] + q0;
                s[l] = s[l] + q1;
            }
        }
        A0 = ((r[0] + r[1]) + (r[2] + r[3])) + ((r[4] + r[5]) + (r[6] + r[7]));
        A1 = ((s[0] + s[1]) + (s[2] + s[3])) + ((s[4] + s[5]) + (s[6] + s[7]));
    }

    float m0 = INFINITY, m1 = INFINITY;
    int i0 = 0, i1 = 0;

    const float4* cb4 = (const float4*)cb;
    float4* l4 = (float4*)ldsC;

    for (int t = 0; t < NTILES; ++t) {
        __syncthreads();
        for (int i = tid; i < D * (KT / 4); i += 256) {
            int d  = i >> 5;
            int c4 = i & 31;
            l4[i] = cb4[d * (K / 4) + t * (KT / 4) + c4];
        }
        __syncthreads();

        for (int j0 = 0; j0 < KT; j0 += 8) {
            float a0[8], a1[8];
            #pragma unroll
            for (int k = 0; k < 8; ++k) { a0[k] = 0.f; a1[k] = 0.f; }
            #pragma unroll
            for (int d = 0; d < D; ++d) {
                float4 ca = l4[d * 32 + (j0 >> 2)];       // broadcast
                float4 cbv = l4[d * 32 + (j0 >> 2) + 1];
                float x0 = xr0[d], x1 = xr1[d];
                // sequential-k FMA chain == OpenBLAS sgemm microkernel order
                a0[0] = fmaf(x0, ca.x,  a0[0]); a0[1] = fmaf(x0, ca.y,  a0[1]);
                a0[2] = fmaf(x0, ca.z,  a0[2]); a0[3] = fmaf(x0, ca.w,  a0[3]);
                a0[4] = fmaf(x0, cbv.x, a0[4]); a0[5] = fmaf(x0, cbv.y, a0[5]);
                a0[6] = fmaf(x0, cbv.z, a0[6]); a0[7] = fmaf(x0, cbv.w, a0[7]);
                a1[0] = fmaf(x1, ca.x,  a1[0]); a1[1] = fmaf(x1, ca.y,  a1[1]);
                a1[2] = fmaf(x1, ca.z,  a1[2]); a1[3] = fmaf(x1, ca.w,  a1[3]);
                a1[4] = fmaf(x1, cbv.x, a1[4]); a1[5] = fmaf(x1, cbv.y, a1[5]);
                a1[6] = fmaf(x1, cbv.z, a1[6]); a1[7] = fmaf(x1, cbv.w, a1[7]);
            }
            #pragma unroll
            for (int k = 0; k < 8; ++k) {
                int j = t * KT + j0 + k;
                float Bj = cnorm[j];
                // dist = fl( fl(A + B_j) - fl(2*M_j) ); *2 exact; contract off
                float t0 = 2.0f * a0[k];
                float s0 = A0 + Bj;
                float d0 = s0 - t0;
                if (d0 < m0) { m0 = d0; i0 = j; }   // strict <, ascending j
                float t1 = 2.0f * a1[k];
                float s1 = A1 + Bj;
                float d1 = s1 - t1;
                if (d1 < m1) { m1 = d1; i1 = j; }
            }
        }
    }

    // ---- gather codebook columns, write out, accumulate loss ----
    float lsum = 0.f;
    float4* o0 = (float4*)(out + row0 * D);
    float4* o1 = (float4*)(out + row1 * D);
    #pragma unroll
    for (int d0 = 0; d0 < D; d0 += 4) {
        float q0 = cb[(d0+0)*K + i0], q1 = cb[(d0+1)*K + i0];
        float q2 = cb[(d0+2)*K + i0], q3 = cb[(d0+3)*K + i0];
        float e0 = q0 - xr0[d0+0], e1 = q1 - xr0[d0+1];
        float e2 = q2 - xr0[d0+2], e3 = q3 - xr0[d0+3];
        lsum += e0*e0 + e1*e1 + e2*e2 + e3*e3;
        o0[d0/4] = make_float4(q0, q1, q2, q3);

        float p0 = cb[(d0+0)*K + i1], p1 = cb[(d0+1)*K + i1];
        float p2 = cb[(d0+2)*K + i1], p3 = cb[(d0+3)*K + i1];
        float f0 = p0 - xr1[d0+0], f1 = p1 - xr1[d0+1];
        float f2 = p2 - xr1[d0+2], f3 = p3 - xr1[d0+3];
        lsum += f0*f0 + f1*f1 + f2*f2 + f3*f3;
        o1[d0/4] = make_float4(p0, p1, p2, p3);
    }

    #pragma unroll
    for (int off = 32; off > 0; off >>= 1) lsum += __shfl_down(lsum, off);
    int lane = tid & 63, wave = tid >> 6;
    if (lane == 0) wavesum[wave] = lsum;
    __syncthreads();
    if (tid == 0) {
        double tot = (double)wavesum[0] + (double)wavesum[1]
                   + (double)wavesum[2] + (double)wavesum[3];
        atomicAdd(loss_acc, tot);
    }
}

__global__ void vq_finalize(const double* __restrict__ acc, float* __restrict__ out) {
    // loss = (1 + beta) * mean((q - x)^2), beta = 0.25
    out[NELEM] = (float)(acc[0] * (1.25 / (double)NELEM));
}

extern "C" void kernel_launch(void* const* d_in, const int* in_sizes, int n_in,
                              void* d_out, int out_size, void* d_ws, size_t ws_size,
                              hipStream_t stream) {
    const float* x  = (const float*)d_in[0];   // [32,64,64,64] fp32
    const float* cb = (const float*)d_in[1];   // [64,512] fp32
    float* out = (float*)d_out;                // [8388608] out + [1] loss
    double* loss_acc = (double*)d_ws;
    float* cnorm = (float*)((char*)d_ws + 16);

    hipMemsetAsync(d_ws, 0, 16, stream);
    vq_cnorm<<<1, 512, 0, stream>>>(cb, cnorm);
    vq_main<<<256, 256, 0, stream>>>(x, cb, cnorm, out, loss_acc);
    vq_finalize<<<1, 1, 0, stream>>>(loss_acc, out);
}